// Round 2
// baseline (472.516 us; speedup 1.0000x reference)
//
#include <hip/hip_runtime.h>
#include <math.h>

#define HH 1024
#define VV 50000
#define NB2 1250           // K2 blocks: 5000 waves, exactly 10 rows/wave

typedef float f4 __attribute__((ext_vector_type(4)));

__device__ __forceinline__ float dot4(f4 a, f4 b) {
    return a.x * b.x + a.y * b.y + a.z * b.z + a.w * b.w;
}

// butterfly reduce over the 64-lane wave: all lanes end with the total
__device__ __forceinline__ float wredsum(float v) {
#pragma unroll
    for (int o = 32; o > 0; o >>= 1) v += __shfl_xor(v, o);
    return v;
}

// ---------------------------------------------------------------------------
// K1: LSTM cell. block = hidden index j (1024 blocks), wave = gate g (4 waves).
// PLAIN cached loads everywhere: W_ih/W_hh (33.5 MB) and out_W (204.8 MB)
// together fit the 256 MiB Infinity Cache, so across iterations the weights
// are L3-resident — nontemporal loads here cost ~36 us (round-1 lesson).
// Also zeroes the K2 last-block ticket (ws is poisoned by the harness).
// ---------------------------------------------------------------------------
__global__ __launch_bounds__(256) void lstm_kernel(
    const int* __restrict__ tok, const float* __restrict__ emb,
    const float* __restrict__ h0, const float* __restrict__ c0,
    const float* __restrict__ W_ih, const float* __restrict__ W_hh,
    const float* __restrict__ b_ih, const float* __restrict__ b_hh,
    float* __restrict__ out,      // d_out: [V logits][H h_new][H c_new]
    int* __restrict__ ticket)
{
    if (blockIdx.x == 0 && threadIdx.x == 0) *ticket = 0;  // visible to K2 at kernel boundary

    __shared__ float sg[4];
    const int g    = threadIdx.x >> 6;               // gate = wave id
    const int lane = threadIdx.x & 63;
    const int j    = blockIdx.x;                     // 0..1023
    const int t    = tok[0];                         // int64 low word
    const float* e = emb + (size_t)t * HH;

    const float* wi = W_ih + (size_t)(g * HH + j) * HH;
    const float* wh = W_hh + (size_t)(g * HH + j) * HH;

    float acc = 0.f;
#pragma unroll
    for (int k = 0; k < 4; ++k) {
        const int idx = k * 256 + lane * 4;
        const f4 a  = *(const f4*)(wi + idx);
        const f4 b  = *(const f4*)(wh + idx);
        const f4 ev = *(const f4*)(e  + idx);
        const f4 hv = *(const f4*)(h0 + idx);
        acc += dot4(a, ev);
        acc += dot4(b, hv);
    }
    acc = wredsum(acc);
    if (lane == 0) sg[g] = acc + b_ih[g * HH + j] + b_hh[g * HH + j];
    __syncthreads();

    if (threadIdx.x == 0) {
        const float si = 1.f / (1.f + expf(-sg[0]));
        const float sf = 1.f / (1.f + expf(-sg[1]));
        const float gg = tanhf(sg[2]);
        const float so = 1.f / (1.f + expf(-sg[3]));
        const float cn = sf * c0[j] + si * gg;
        const float hn = so * tanhf(cn);
        out[VV + j]      = hn;
        out[VV + HH + j] = cn;
    }
}

// ---------------------------------------------------------------------------
// K2: logits[r] = out_W[r]·h + out_b[r], 10 rows/wave.
// Phase 1: 10 independent dot accumulators (40 cached float4 loads, max MLP).
// Phase 2: 10 butterfly reductions interleaved (6 stages x 10-way ILP).
// Phase 3: batched bias/max/sumexp, per-block (m,s) partial.
// Last block (device-scope ticket) merges the 1250 partials -> logZ.
// ---------------------------------------------------------------------------
__global__ __launch_bounds__(256) void logits_kernel(
    const float* __restrict__ out_W, const float* __restrict__ out_b,
    const float* __restrict__ h,      // = d_out + V (written by K1)
    float* __restrict__ logits,       // = d_out
    float2* __restrict__ part,        // [NB2] (m_b, s_b)
    int* __restrict__ ticket,         // zeroed by K1
    float* __restrict__ logz)
{
    __shared__ float2 sp[4];
    __shared__ int slast;
    const int wid  = threadIdx.x >> 6;
    const int lane = threadIdx.x & 63;
    const int gw   = blockIdx.x * 4 + wid;           // 0..4999

    f4 hv[4];
#pragma unroll
    for (int k = 0; k < 4; ++k)
        hv[k] = *(const f4*)(h + k * 256 + lane * 4);

    // ---- phase 1: dots only -------------------------------------------------
    float acc[10];
#pragma unroll
    for (int i = 0; i < 10; ++i) {
        const float* w = out_W + (size_t)(gw + i * 5000) * HH;
        float a = 0.f;
#pragma unroll
        for (int k = 0; k < 4; ++k) {
            const f4 x = *((const f4*)(w + k * 256) + lane);
            a += dot4(x, hv[k]);
        }
        acc[i] = a;
    }

    // ---- phase 2: 10 interleaved butterfly reductions ----------------------
#pragma unroll
    for (int o = 32; o > 0; o >>= 1) {
#pragma unroll
        for (int i = 0; i < 10; ++i) acc[i] += __shfl_xor(acc[i], o);
    }

    // ---- phase 3: bias, store, max, sumexp (wave-uniform, no divergence) ---
    float m = -INFINITY;
#pragma unroll
    for (int i = 0; i < 10; ++i) {
        acc[i] += out_b[gw + i * 5000];
        m = fmaxf(m, acc[i]);
    }
    if (lane == 0) {
#pragma unroll
        for (int i = 0; i < 10; ++i) logits[gw + i * 5000] = acc[i];
    }
    float s = 0.f;
#pragma unroll
    for (int i = 0; i < 10; ++i) s += expf(acc[i] - m);

    if (lane == 0) sp[wid] = make_float2(m, s);
    __syncthreads();
    if (threadIdx.x == 0) {
        float2 p = sp[0];
#pragma unroll
        for (int w = 1; w < 4; ++w) {
            const float2 q = sp[w];
            const float nm = fmaxf(p.x, q.x);
            p.y = p.y * expf(p.x - nm) + q.y * expf(q.x - nm);
            p.x = nm;
        }
        part[blockIdx.x] = p;
        __threadfence();                              // release partial
        slast = (atomicAdd(ticket, 1) == NB2 - 1) ? 1 : 0;
    }
    __syncthreads();
    if (!slast) return;

    // ---- last block: merge 1250 (m,s) partials -> logZ = M + log(S) --------
    __threadfence();                                  // acquire others' partials
    __shared__ float2 red[256];
    float mm = -INFINITY, ss = 0.f;
    for (int i = threadIdx.x; i < NB2; i += 256) {
        const float2 q = part[i];
        const float nm = fmaxf(mm, q.x);
        ss = ss * expf(mm - nm) + q.y * expf(q.x - nm);
        mm = nm;
    }
    red[threadIdx.x] = make_float2(mm, ss);
    __syncthreads();
    for (int st = 128; st > 0; st >>= 1) {
        if (threadIdx.x < st) {
            float2 p = red[threadIdx.x], q = red[threadIdx.x + st];
            const float nm = fmaxf(p.x, q.x);
            p.y = p.y * expf(p.x - nm) + q.y * expf(q.x - nm);
            p.x = nm;
            red[threadIdx.x] = p;
        }
        __syncthreads();
    }
    if (threadIdx.x == 0) *logz = red[0].x + logf(red[0].y);
}

// ---------------------------------------------------------------------------
// K3: logits[v] -= logZ, float4-wide (50000 = 12500 float4)
// ---------------------------------------------------------------------------
__global__ __launch_bounds__(256) void sub_kernel(
    f4* __restrict__ logits, const float* __restrict__ logz)
{
    const float lz = *logz;
    const int v = blockIdx.x * 256 + threadIdx.x;
    if (v < VV / 4) {
        f4 t = logits[v];
        t.x -= lz; t.y -= lz; t.z -= lz; t.w -= lz;
        logits[v] = t;
    }
}

extern "C" void kernel_launch(void* const* d_in, const int* in_sizes, int n_in,
                              void* d_out, int out_size, void* d_ws, size_t ws_size,
                              hipStream_t stream) {
    const int*   tok   = (const int*)  d_in[0];
    const float* h0    = (const float*)d_in[1];
    const float* c0    = (const float*)d_in[2];
    // d_in[3] encoder_outputs — dead code, never read
    const float* emb   = (const float*)d_in[4];
    // d_in[5..8] attn_W, attn_b, comb_W, comb_b — dead code, never read
    const float* W_ih  = (const float*)d_in[9];
    const float* W_hh  = (const float*)d_in[10];
    const float* b_ih  = (const float*)d_in[11];
    const float* b_hh  = (const float*)d_in[12];
    const float* out_W = (const float*)d_in[13];
    const float* out_b = (const float*)d_in[14];

    float* out = (float*)d_out;

    float2* part   = (float2*)d_ws;           // [NB2] (m_b, s_b) partials
    float*  logz   = (float*)(part + NB2);
    int*    ticket = (int*)(logz + 1);

    lstm_kernel<<<1024, 256, 0, stream>>>(tok, emb, h0, c0, W_ih, W_hh, b_ih, b_hh,
                                          out, ticket);
    logits_kernel<<<NB2, 256, 0, stream>>>(out_W, out_b, out + VV, out, part,
                                           ticket, logz);
    sub_kernel<<<(VV / 4 + 255) / 256, 256, 0, stream>>>((f4*)out, logz);
}

// Round 3
// 414.444 us; speedup vs baseline: 1.1401x; 1.1401x over previous
//
#include <hip/hip_runtime.h>
#include <math.h>

#define HH 1024
#define VV 50000
#define NB2 3125           // K2 blocks: 12500 waves, 4 consecutive rows/wave

typedef float f4 __attribute__((ext_vector_type(4)));

__device__ __forceinline__ float dot4(f4 a, f4 b) {
    return a.x * b.x + a.y * b.y + a.z * b.z + a.w * b.w;
}

// ---------------------------------------------------------------------------
// K1: LSTM cell. block = hidden index j (1024 blocks), wave = gate g (4 waves).
// Round-0 proven version: plain cached loads (weights are L3-resident across
// iterations; nt loads cost ~20 us — round-1/2 lesson).
// ---------------------------------------------------------------------------
__global__ __launch_bounds__(256) void lstm_kernel(
    const int* __restrict__ tok, const float* __restrict__ emb,
    const float* __restrict__ h0, const float* __restrict__ c0,
    const float* __restrict__ W_ih, const float* __restrict__ W_hh,
    const float* __restrict__ b_ih, const float* __restrict__ b_hh,
    float* __restrict__ out)      // d_out: [V logits][H h_new][H c_new]
{
    __shared__ float sg[4];
    const int g    = threadIdx.x >> 6;               // gate = wave id
    const int lane = threadIdx.x & 63;
    const int j    = blockIdx.x;                     // 0..1023
    const int t    = tok[0];                         // int64 low word
    const float* e = emb + (size_t)t * HH;

    const float* wi = W_ih + (size_t)(g * HH + j) * HH;
    const float* wh = W_hh + (size_t)(g * HH + j) * HH;

    float acc = 0.f;
#pragma unroll
    for (int k = 0; k < 4; ++k) {
        const int idx = k * 256 + lane * 4;
        const f4 a  = *(const f4*)(wi + idx);
        const f4 b  = *(const f4*)(wh + idx);
        const f4 ev = *(const f4*)(e  + idx);
        const f4 hv = *(const f4*)(h0 + idx);
        acc += dot4(a, ev);
        acc += dot4(b, hv);
    }
#pragma unroll
    for (int o = 32; o > 0; o >>= 1) acc += __shfl_xor(acc, o);
    if (lane == 0) sg[g] = acc + b_ih[g * HH + j] + b_hh[g * HH + j];
    __syncthreads();

    if (threadIdx.x == 0) {
        const float si = 1.f / (1.f + expf(-sg[0]));
        const float sf = 1.f / (1.f + expf(-sg[1]));
        const float gg = tanhf(sg[2]);
        const float so = 1.f / (1.f + expf(-sg[3]));
        const float cn = sf * c0[j] + si * gg;
        const float hn = so * tanhf(cn);
        out[VV + j]      = hn;
        out[VV + HH + j] = cn;
    }
}

// ---------------------------------------------------------------------------
// K2: logits[r] = out_W[r]·h + out_b[r]. 4 CONSECUTIVE rows per wave,
// 3125 blocks x 4 waves = 12500 waves (2.5x round-2) for latency hiding.
// 16 independent 1-KB loads per wave, only 4 accumulators -> compiler can
// keep the full load set in flight (round-2 was 36 VGPR / ~2 loads in
// flight -> 1.4 TB/s latency-bound; this is the fix).
// ---------------------------------------------------------------------------
__global__ __launch_bounds__(256) void logits_kernel(
    const float* __restrict__ out_W, const float* __restrict__ out_b,
    const float* __restrict__ h,      // = d_out + V (written by K1)
    float* __restrict__ logits,       // = d_out
    float2* __restrict__ part)        // [NB2] (m_b, s_b)
{
    __shared__ float2 sp[4];
    const int wid  = threadIdx.x >> 6;
    const int lane = threadIdx.x & 63;
    const int gw   = blockIdx.x * 4 + wid;           // 0..12499
    const int r0   = gw * 4;                         // first of 4 rows

    f4 hv[4];
#pragma unroll
    for (int k = 0; k < 4; ++k)
        hv[k] = *(const f4*)(h + k * 256 + lane * 4);

    // ---- 16 independent loads, 4 accumulators ------------------------------
    float acc[4];
#pragma unroll
    for (int j = 0; j < 4; ++j) {
        const f4* w = (const f4*)(out_W + (size_t)(r0 + j) * HH);
        const f4 x0 = w[lane];
        const f4 x1 = w[lane + 64];
        const f4 x2 = w[lane + 128];
        const f4 x3 = w[lane + 192];
        acc[j] = (dot4(x0, hv[0]) + dot4(x1, hv[1]))
               + (dot4(x2, hv[2]) + dot4(x3, hv[3]));
    }

    // ---- 4 interleaved butterfly reductions (6 stages x 4-way ILP) ---------
#pragma unroll
    for (int o = 32; o > 0; o >>= 1) {
#pragma unroll
        for (int j = 0; j < 4; ++j) acc[j] += __shfl_xor(acc[j], o);
    }

    // ---- bias (one 16B load), store (one 16B store), max/sumexp ------------
    const f4 vb = *(const f4*)(out_b + r0);
    acc[0] += vb.x; acc[1] += vb.y; acc[2] += vb.z; acc[3] += vb.w;
    if (lane == 0) {
        f4 st; st.x = acc[0]; st.y = acc[1]; st.z = acc[2]; st.w = acc[3];
        *(f4*)(logits + r0) = st;
    }
    const float m = fmaxf(fmaxf(acc[0], acc[1]), fmaxf(acc[2], acc[3]));
    const float s = expf(acc[0] - m) + expf(acc[1] - m)
                  + expf(acc[2] - m) + expf(acc[3] - m);

    if (lane == 0) sp[wid] = make_float2(m, s);
    __syncthreads();
    if (threadIdx.x == 0) {
        float2 p = sp[0];
#pragma unroll
        for (int w = 1; w < 4; ++w) {
            const float2 q = sp[w];
            const float nm = fmaxf(p.x, q.x);
            p.y = p.y * expf(p.x - nm) + q.y * expf(q.x - nm);
            p.x = nm;
        }
        part[blockIdx.x] = p;
    }
}

// ---------------------------------------------------------------------------
// K3: merged logZ + subtract. Each of the 49 blocks REDUNDANTLY merges the
// 3125 partials (25 KB, L2-hot) -> logZ, then subtracts from its f4 slice.
// No cross-block sync, one fewer launch than separate logz/sub kernels.
// ---------------------------------------------------------------------------
__global__ __launch_bounds__(256) void logz_sub_kernel(
    const float2* __restrict__ part, f4* __restrict__ logits)
{
    __shared__ float2 red[256];
    float m = -INFINITY, s = 0.f;
    for (int i = threadIdx.x; i < NB2; i += 256) {
        const float2 q = part[i];
        const float nm = fmaxf(m, q.x);
        s = s * expf(m - nm) + q.y * expf(q.x - nm);
        m = nm;
    }
    red[threadIdx.x] = make_float2(m, s);
    __syncthreads();
    for (int st = 128; st > 0; st >>= 1) {
        if (threadIdx.x < st) {
            float2 p = red[threadIdx.x], q = red[threadIdx.x + st];
            const float nm = fmaxf(p.x, q.x);
            p.y = p.y * expf(p.x - nm) + q.y * expf(q.x - nm);
            p.x = nm;
            red[threadIdx.x] = p;
        }
        __syncthreads();
    }
    const float lz = red[0].x + logf(red[0].y);

    const int v = blockIdx.x * 256 + threadIdx.x;
    if (v < VV / 4) {
        f4 t = logits[v];
        t.x -= lz; t.y -= lz; t.z -= lz; t.w -= lz;
        logits[v] = t;
    }
}

extern "C" void kernel_launch(void* const* d_in, const int* in_sizes, int n_in,
                              void* d_out, int out_size, void* d_ws, size_t ws_size,
                              hipStream_t stream) {
    const int*   tok   = (const int*)  d_in[0];
    const float* h0    = (const float*)d_in[1];
    const float* c0    = (const float*)d_in[2];
    // d_in[3] encoder_outputs — dead code, never read
    const float* emb   = (const float*)d_in[4];
    // d_in[5..8] attn_W, attn_b, comb_W, comb_b — dead code, never read
    const float* W_ih  = (const float*)d_in[9];
    const float* W_hh  = (const float*)d_in[10];
    const float* b_ih  = (const float*)d_in[11];
    const float* b_hh  = (const float*)d_in[12];
    const float* out_W = (const float*)d_in[13];
    const float* out_b = (const float*)d_in[14];

    float* out = (float*)d_out;

    float2* part = (float2*)d_ws;             // [NB2] (m_b, s_b) partials

    lstm_kernel<<<1024, 256, 0, stream>>>(tok, emb, h0, c0, W_ih, W_hh,
                                          b_ih, b_hh, out);
    logits_kernel<<<NB2, 256, 0, stream>>>(out_W, out_b, out + VV, out, part);
    logz_sub_kernel<<<(VV / 4 + 255) / 256, 256, 0, stream>>>(part, (f4*)out);
}